// Round 1
// baseline (205.325 us; speedup 1.0000x reference)
//
#include <hip/hip_runtime.h>

// MinEuclideanDistBlock: x(32,8,4096) f32, shapelets(8,128,64) f32 -> out(32,1,128) f32
// out[b,k] = min_w sum_c sqrt( xnorm[b,c,w] + snorm[c,k] - 2*sum_s x[b,c,w+s]*h[c,k,s] )
//
// R3 -> R4 changes (post-mortem: MfmaUtil 11%, VALUBusy 30%, Occ 18% -> latency-bound,
// 2 barriers + unoverlapped staging latency per c-iter):
//  - Bs staging is now __builtin_amdgcn_global_load_lds width=16 (async DMA, no VALU,
//    no VGPR round-trip). prep_kernel bakes the bank-conflict XOR swizzle
//    (byte ^= (k&7)<<4 within each 128B row) into hbf, so the DMA is linear
//    (wave-uniform base + lane*16) and the ds_read_b128 side applies the swizzle.
//    Bs pad dropped (80 -> 64 elem rows).
//  - Double-buffered Xr and Bs, ONE __syncthreads per c-iter: issue c+1's Bs DMA and
//    x global loads (to regs) at iter start, compute c, then f2bf+ds_write Xr[buf^1]
//    late (T14 async-STAGE split). Prefetch latency hides under MFMA+sqrt compute;
//    the barrier's implicit vmcnt(0) drain is the handshake.
//  - Staging index math (incl. the /96) hoisted out of the c-loop (c-invariant).
//  - LDS 47.4KB -> 3 blocks/CU (__launch_bounds__(256,3)).

typedef short short8 __attribute__((ext_vector_type(8)));
typedef float f32x4 __attribute__((ext_vector_type(4)));

constexpr int Bn = 32, Cn = 8, Ln = 4096, Kn = 128, Sn = 64;
constexpr int Wn = Ln - Sn + 1;          // 4033
constexpr int WT = 128;                  // windows per block
constexpr int NWT = (Wn + WT - 1) / WT;  // 32
constexpr int BDIM = 256;

typedef const __attribute__((address_space(1))) unsigned int gas_u32;
typedef __attribute__((address_space(3))) unsigned int las_u32;

__device__ __forceinline__ unsigned int f2bf(float f) {
  unsigned int u = __float_as_uint(f);
  u += 0x7FFFu + ((u >> 16) & 1u);       // round-to-nearest-even
  return u >> 16;
}

// ws layout: [0, 128KB): ushort hbf[C][K][S] = bf16(-2*h), byte-swizzled ^((k&7)<<4)
//            [128KB, +4KB): float snorm[C][K]
__global__ void prep_kernel(const float* __restrict__ sh,
                            unsigned int* __restrict__ out,
                            unsigned short* __restrict__ hbf,
                            float* __restrict__ snorm) {
  int gid = blockIdx.x * blockDim.x + threadIdx.x;  // 0..4095
  out[gid] = 0x7F7FFFFFu;                           // FLT_MAX bits (Bn*Kn == 4096)
  if (gid < Cn * Kn) {
    const float4* row = (const float4*)(sh + (size_t)gid * Sn);
    char* rowb = (char*)hbf + (size_t)gid * (Sn * 2);   // 128B row
    const unsigned int sw = (gid & 7u) << 4;            // (k&7)<<4 byte swizzle
    float a = 0.f;
    #pragma unroll
    for (int i = 0; i < 16; ++i) {
      float4 v = row[i];
      a += v.x * v.x + v.y * v.y + v.z * v.z + v.w * v.w;
      unsigned int p0 = f2bf(-2.f * v.x) | (f2bf(-2.f * v.y) << 16);
      unsigned int p1 = f2bf(-2.f * v.z) | (f2bf(-2.f * v.w) << 16);
      *(uint2*)(rowb + ((8u * i) ^ sw)) = make_uint2(p0, p1);  // stays 8B-aligned
    }
    snorm[gid] = a;
  }
}

__launch_bounds__(BDIM, 3)
__global__ void med_kernel(const float* __restrict__ x,
                           const unsigned short* __restrict__ hbf,
                           const float* __restrict__ snorm,
                           unsigned int* __restrict__ out) {
  constexpr int XRS = 200;  // Xr row stride (elems); 400B, 16B-aligned rows
  __shared__ __align__(16) unsigned short Xr[2][8 * XRS];   // 2 x 3.2KB
  __shared__ __align__(16) unsigned short Bs[2][Kn * Sn];   // 2 x 16KB, swizzled
  __shared__ __align__(16) float xnormC[Cn * WT];
  __shared__ __align__(16) float snormC[Cn * Kn];

  const int tid  = threadIdx.x;
  const int b    = blockIdx.y;
  const int w0   = blockIdx.x * WT;
  const int lane = tid & 63;
  const int wv   = tid >> 6;     // wave 0..3
  const int quad = lane >> 4;    // 0..3
  const int n16  = lane & 15;
  const int wbase = wv * 32;     // this wave's window offset in tile

  const float* xb = x + (size_t)b * Cn * Ln;

  // ---- B staging: linear global->LDS DMA of pre-swizzled 16KB c-slice ----
  auto stage_b = [&](int bufi, int c) {
    const char* src = (const char*)hbf + (size_t)c * (Kn * Sn * 2);
    char* dst = (char*)&Bs[bufi][0];
    #pragma unroll
    for (int rep = 0; rep < 4; ++rep) {
      int q16 = (tid + rep * BDIM) * 16;   // lane-linear 16B chunks
      __builtin_amdgcn_global_load_lds((gas_u32*)(src + q16), (las_u32*)(dst + q16),
                                       16, 0, 0);
    }
  };

  // ---- X staging: c-invariant index math hoisted; load early / write late ----
  int x_lds[3], x_g[3];
  #pragma unroll
  for (int rep = 0; rep < 3; ++rep) {
    int pid = tid + rep * BDIM;       // 0..767
    int r = pid / 96;
    int p = pid - r * 96;             // pair index 0..95 -> elems 2p,2p+1
    x_lds[rep] = r * XRS + 2 * p;
    x_g[rep] = w0 + r + 2 * p;
  }
  float xf[3][2];
  auto load_x = [&](int c) {
    const float* xc = xb + (size_t)c * Ln;
    #pragma unroll
    for (int rep = 0; rep < 3; ++rep) {
      int i0 = x_g[rep];
      xf[rep][0] = (i0 < Ln) ? xc[i0] : 0.f;
      xf[rep][1] = (i0 + 1 < Ln) ? xc[i0 + 1] : 0.f;
    }
  };
  auto write_x = [&](int bufi) {
    #pragma unroll
    for (int rep = 0; rep < 3; ++rep)
      *(unsigned int*)(&Xr[bufi][x_lds[rep]]) =
          f2bf(xf[rep][0]) | (f2bf(xf[rep][1]) << 16);
  };

  // snorm: one float4 per thread from prep output
  ((float4*)snormC)[tid] = ((const float4*)snorm)[tid];

  // ---- prologue: stage c=0 into buf 0 (DMA overlaps xnorm compute) ----
  stage_b(0, 0);
  load_x(0);

  // xnorm: 256 threads = 8c x 32 groups, 4 windows each (rolling update), fp32-exact
  {
    int c  = tid >> 5;
    int m0 = (tid & 31) * 4;
    const float* xc = xb + c * Ln;
    auto xq = [&](int i) -> float {
      float v = (i < Ln) ? xc[i] : 0.f;
      return v * v;
    };
    float s0 = 0.f;
    for (int s = 0; s < Sn; ++s) s0 += xq(w0 + m0 + s);
    float s1 = s0 - xq(w0 + m0 + 0) + xq(w0 + m0 + 64);
    float s2 = s1 - xq(w0 + m0 + 1) + xq(w0 + m0 + 65);
    float s3 = s2 - xq(w0 + m0 + 2) + xq(w0 + m0 + 66);
    xnormC[c * WT + m0 + 0] = s0;
    xnormC[c * WT + m0 + 1] = s1;
    xnormC[c * WT + m0 + 2] = s2;
    xnormC[c * WT + m0 + 3] = s3;
  }
  write_x(0);
  __syncthreads();  // drains prologue DMA (implicit vmcnt(0)) + covers norm writes

  float dist[2][8][4] = {};  // [mtile][ntile2][reg] summed distance over c

  for (int c = 0; c < Cn; ++c) {
    const int buf = c & 1;

    // issue next channel's prefetch BEFORE compute (hides under MFMA+sqrt)
    if (c + 1 < Cn) {
      stage_b(buf ^ 1, c + 1);   // async DMA into other Bs buffer
      load_x(c + 1);             // global loads into regs, waited at write_x
    }

    // xnorm for this wave's 32 windows (C/D row = quad*4+reg) — one b128 each
    float4 xn[2];
    #pragma unroll
    for (int mt = 0; mt < 2; ++mt)
      xn[mt] = *(const float4*)(&xnormC[c * WT + wbase + mt * 16 + quad * 4]);

    // A fragments: lane m = n16, k = quad*8+j (+ks*32); one aligned b128 each
    short8 af[2][2];
    #pragma unroll
    for (int mt = 0; mt < 2; ++mt)
      #pragma unroll
      for (int ks = 0; ks < 2; ++ks) {
        int i = wbase + mt * 16 + n16 + ks * 32 + quad * 8;
        af[mt][ks] = *(const short8*)(&Xr[buf][(i & 7) * XRS + (i >> 3) * 8]);
      }

    const char* bsb = (const char*)&Bs[buf][0];
    #pragma unroll
    for (int pass = 0; pass < 2; ++pass) {
      short8 bfr[4][2];
      float sn[4];
      #pragma unroll
      for (int nt = 0; nt < 4; ++nt) {
        int ksh = pass * 64 + nt * 16 + n16;
        sn[nt] = snormC[c * Kn + ksh];
        #pragma unroll
        for (int ks = 0; ks < 2; ++ks) {
          int off = (ksh * 128 + ks * 64 + quad * 16) ^ ((ksh & 7) << 4);
          bfr[nt][ks] = *(const short8*)(bsb + off);
        }
      }
      #pragma unroll
      for (int mt = 0; mt < 2; ++mt)
        #pragma unroll
        for (int nt = 0; nt < 4; ++nt) {
          f32x4 acc;
          #pragma unroll
          for (int rg = 0; rg < 4; ++rg) acc[rg] = xn[mt][rg] + sn[nt];
          acc = __builtin_amdgcn_mfma_f32_16x16x32_bf16(af[mt][0], bfr[nt][0], acc, 0, 0, 0);
          acc = __builtin_amdgcn_mfma_f32_16x16x32_bf16(af[mt][1], bfr[nt][1], acc, 0, 0, 0);
          // acc == d2 (norms preloaded in C, -2 folded into B)
          #pragma unroll
          for (int rg = 0; rg < 4; ++rg)
            dist[mt][pass * 4 + nt][rg] += __builtin_amdgcn_sqrtf(acc[rg]);
        }
    }

    // late half of async-STAGE: convert + write next x tile into other buffer
    if (c + 1 < Cn) write_x(buf ^ 1);
    __syncthreads();  // one barrier per c-iter: publishes Xr writes + drains Bs DMA
  }

  // ---- min over windows, then global combine ----
  const int wql = w0 + wbase + quad * 4;
  #pragma unroll
  for (int nt2 = 0; nt2 < 8; ++nt2) {
    float v = 3.4e38f;
    #pragma unroll
    for (int mt = 0; mt < 2; ++mt)
      #pragma unroll
      for (int rg = 0; rg < 4; ++rg) {
        int wg = wql + mt * 16 + rg;
        float d = (wg < Wn) ? dist[mt][nt2][rg] : 3.4e38f;
        v = fminf(v, d);
      }
    v = fminf(v, __shfl_xor(v, 16, 64));
    v = fminf(v, __shfl_xor(v, 32, 64));
    if (lane < 16)
      atomicMin(&out[b * Kn + nt2 * 16 + n16], __float_as_uint(v));
  }
}

extern "C" void kernel_launch(void* const* d_in, const int* in_sizes, int n_in,
                              void* d_out, int out_size, void* d_ws, size_t ws_size,
                              hipStream_t stream) {
  const float* x  = (const float*)d_in[0];
  const float* sh = (const float*)d_in[1];
  unsigned int* out = (unsigned int*)d_out;
  unsigned short* hbf = (unsigned short*)d_ws;                      // 128 KB
  float* snorm = (float*)((char*)d_ws + (size_t)Cn * Kn * Sn * 2);  // +4 KB
  hipLaunchKernelGGL(prep_kernel, dim3(16), dim3(256), 0, stream, sh, out, hbf, snorm);
  hipLaunchKernelGGL(med_kernel, dim3(NWT, Bn), dim3(BDIM), 0, stream, x, hbf, snorm, out);
}

// Round 2
// 110.432 us; speedup vs baseline: 1.8593x; 1.8593x over previous
//
#include <hip/hip_runtime.h>

// MinEuclideanDistBlock: x(32,8,4096) f32, shapelets(8,128,64) f32 -> out(32,1,128) f32
// out[b,k] = min_w sum_c sqrt( xnorm[b,c,w] + snorm[c,k] - 2*sum_s x[b,c,w+s]*h[c,k,s] )
//
// R4 -> R5 changes (post-mortem: WRITE_SIZE 2MB->114MB + VGPR 112->84 = launch_bounds(256,3)
// forced a catastrophic scratch spill; the pipeline never ran from registers):
//  - __launch_bounds__(256,2) restored (R3-proven budget; no spill at ~120-130 VGPR demand).
//  - Inner loop restructured nt-outer/mt-inner with per-nt B-fragment loads: peak live set
//    drops ~24 VGPRs (bfr 32->8 live), aiming for the <=128 VGPR / 4-waves-per-SIMD tier.
//  - Kept from R4: pre-swizzled hbf + global_load_lds width=16 B-staging (no VALU, no VGPR
//    round-trip), double-buffered Xr/Bs, ONE barrier per c-iter, async x-stage split
//    (load early to regs / f2bf+ds_write late).

typedef short short8 __attribute__((ext_vector_type(8)));
typedef float f32x4 __attribute__((ext_vector_type(4)));

constexpr int Bn = 32, Cn = 8, Ln = 4096, Kn = 128, Sn = 64;
constexpr int Wn = Ln - Sn + 1;          // 4033
constexpr int WT = 128;                  // windows per block
constexpr int NWT = (Wn + WT - 1) / WT;  // 32
constexpr int BDIM = 256;

typedef const __attribute__((address_space(1))) unsigned int gas_u32;
typedef __attribute__((address_space(3))) unsigned int las_u32;

__device__ __forceinline__ unsigned int f2bf(float f) {
  unsigned int u = __float_as_uint(f);
  u += 0x7FFFu + ((u >> 16) & 1u);       // round-to-nearest-even
  return u >> 16;
}

// ws layout: [0, 128KB): ushort hbf[C][K][S] = bf16(-2*h), byte-swizzled ^((k&7)<<4)
//            [128KB, +4KB): float snorm[C][K]
__global__ void prep_kernel(const float* __restrict__ sh,
                            unsigned int* __restrict__ out,
                            unsigned short* __restrict__ hbf,
                            float* __restrict__ snorm) {
  int gid = blockIdx.x * blockDim.x + threadIdx.x;  // 0..4095
  out[gid] = 0x7F7FFFFFu;                           // FLT_MAX bits (Bn*Kn == 4096)
  if (gid < Cn * Kn) {
    const float4* row = (const float4*)(sh + (size_t)gid * Sn);
    char* rowb = (char*)hbf + (size_t)gid * (Sn * 2);   // 128B row
    const unsigned int sw = (gid & 7u) << 4;            // (k&7)<<4 byte swizzle
    float a = 0.f;
    #pragma unroll
    for (int i = 0; i < 16; ++i) {
      float4 v = row[i];
      a += v.x * v.x + v.y * v.y + v.z * v.z + v.w * v.w;
      unsigned int p0 = f2bf(-2.f * v.x) | (f2bf(-2.f * v.y) << 16);
      unsigned int p1 = f2bf(-2.f * v.z) | (f2bf(-2.f * v.w) << 16);
      *(uint2*)(rowb + ((8u * i) ^ sw)) = make_uint2(p0, p1);  // stays 8B-aligned
    }
    snorm[gid] = a;
  }
}

__launch_bounds__(BDIM, 2)
__global__ void med_kernel(const float* __restrict__ x,
                           const unsigned short* __restrict__ hbf,
                           const float* __restrict__ snorm,
                           unsigned int* __restrict__ out) {
  constexpr int XRS = 200;  // Xr row stride (elems); 400B, 16B-aligned rows
  __shared__ __align__(16) unsigned short Xr[2][8 * XRS];   // 2 x 3.2KB
  __shared__ __align__(16) unsigned short Bs[2][Kn * Sn];   // 2 x 16KB, swizzled
  __shared__ __align__(16) float xnormC[Cn * WT];
  __shared__ __align__(16) float snormC[Cn * Kn];

  const int tid  = threadIdx.x;
  const int b    = blockIdx.y;
  const int w0   = blockIdx.x * WT;
  const int lane = tid & 63;
  const int wv   = tid >> 6;     // wave 0..3
  const int quad = lane >> 4;    // 0..3
  const int n16  = lane & 15;
  const int wbase = wv * 32;     // this wave's window offset in tile

  const float* xb = x + (size_t)b * Cn * Ln;

  // ---- B staging: linear global->LDS DMA of pre-swizzled 16KB c-slice ----
  auto stage_b = [&](int bufi, int c) {
    const char* src = (const char*)hbf + (size_t)c * (Kn * Sn * 2);
    char* dst = (char*)&Bs[bufi][0];
    #pragma unroll
    for (int rep = 0; rep < 4; ++rep) {
      int q16 = (tid + rep * BDIM) * 16;   // lane-linear 16B chunks
      __builtin_amdgcn_global_load_lds((gas_u32*)(src + q16), (las_u32*)(dst + q16),
                                       16, 0, 0);
    }
  };

  // ---- X staging: c-invariant index math hoisted; load early / write late ----
  int x_lds[3], x_g[3];
  #pragma unroll
  for (int rep = 0; rep < 3; ++rep) {
    int pid = tid + rep * BDIM;       // 0..767
    int r = pid / 96;
    int p = pid - r * 96;             // pair index 0..95 -> elems 2p,2p+1
    x_lds[rep] = r * XRS + 2 * p;
    x_g[rep] = w0 + r + 2 * p;
  }
  float xf[3][2];
  auto load_x = [&](int c) {
    const float* xc = xb + (size_t)c * Ln;
    #pragma unroll
    for (int rep = 0; rep < 3; ++rep) {
      int i0 = x_g[rep];
      xf[rep][0] = (i0 < Ln) ? xc[i0] : 0.f;
      xf[rep][1] = (i0 + 1 < Ln) ? xc[i0 + 1] : 0.f;
    }
  };
  auto write_x = [&](int bufi) {
    #pragma unroll
    for (int rep = 0; rep < 3; ++rep)
      *(unsigned int*)(&Xr[bufi][x_lds[rep]]) =
          f2bf(xf[rep][0]) | (f2bf(xf[rep][1]) << 16);
  };

  // snorm: one float4 per thread from prep output
  ((float4*)snormC)[tid] = ((const float4*)snorm)[tid];

  // ---- prologue: stage c=0 into buf 0 (DMA overlaps xnorm compute) ----
  stage_b(0, 0);
  load_x(0);

  // xnorm: 256 threads = 8c x 32 groups, 4 windows each (rolling update), fp32-exact
  {
    int c  = tid >> 5;
    int m0 = (tid & 31) * 4;
    const float* xc = xb + c * Ln;
    auto xq = [&](int i) -> float {
      float v = (i < Ln) ? xc[i] : 0.f;
      return v * v;
    };
    float s0 = 0.f;
    for (int s = 0; s < Sn; ++s) s0 += xq(w0 + m0 + s);
    float s1 = s0 - xq(w0 + m0 + 0) + xq(w0 + m0 + 64);
    float s2 = s1 - xq(w0 + m0 + 1) + xq(w0 + m0 + 65);
    float s3 = s2 - xq(w0 + m0 + 2) + xq(w0 + m0 + 66);
    xnormC[c * WT + m0 + 0] = s0;
    xnormC[c * WT + m0 + 1] = s1;
    xnormC[c * WT + m0 + 2] = s2;
    xnormC[c * WT + m0 + 3] = s3;
  }
  write_x(0);
  __syncthreads();  // drains prologue DMA (implicit vmcnt(0)) + covers norm writes

  float dist[2][8][4] = {};  // [mtile][ntile2][reg] summed distance over c

  for (int c = 0; c < Cn; ++c) {
    const int buf = c & 1;

    // issue next channel's prefetch BEFORE compute (hides under MFMA+sqrt)
    if (c + 1 < Cn) {
      stage_b(buf ^ 1, c + 1);   // async DMA into other Bs buffer
      load_x(c + 1);             // global loads into regs, waited at write_x
    }

    // xnorm for this wave's 32 windows (C/D row = quad*4+reg) — one b128 each
    float4 xn[2];
    #pragma unroll
    for (int mt = 0; mt < 2; ++mt)
      xn[mt] = *(const float4*)(&xnormC[c * WT + wbase + mt * 16 + quad * 4]);

    // A fragments: lane m = n16, k = quad*8+j (+ks*32); one aligned b128 each
    short8 af[2][2];
    #pragma unroll
    for (int mt = 0; mt < 2; ++mt)
      #pragma unroll
      for (int ks = 0; ks < 2; ++ks) {
        int i = wbase + mt * 16 + n16 + ks * 32 + quad * 8;
        af[mt][ks] = *(const short8*)(&Xr[buf][(i & 7) * XRS + (i >> 3) * 8]);
      }

    // nt-outer / mt-inner: only one (b0,b1) pair (8 VGPRs) live at a time
    const char* bsb = (const char*)&Bs[buf][0];
    #pragma unroll
    for (int pass = 0; pass < 2; ++pass) {
      #pragma unroll
      for (int nt = 0; nt < 4; ++nt) {
        int ksh = pass * 64 + nt * 16 + n16;
        float sn = snormC[c * Kn + ksh];
        int boff = (ksh * 128 + quad * 16) ^ ((ksh & 7) << 4);
        short8 b0 = *(const short8*)(bsb + (boff ^ 0));
        short8 b1 = *(const short8*)(bsb + (boff ^ 64));  // ks=1: +64B, swizzle-safe
        #pragma unroll
        for (int mt = 0; mt < 2; ++mt) {
          f32x4 acc;
          #pragma unroll
          for (int rg = 0; rg < 4; ++rg) acc[rg] = xn[mt][rg] + sn;
          acc = __builtin_amdgcn_mfma_f32_16x16x32_bf16(af[mt][0], b0, acc, 0, 0, 0);
          acc = __builtin_amdgcn_mfma_f32_16x16x32_bf16(af[mt][1], b1, acc, 0, 0, 0);
          // acc == d2 (norms preloaded in C, -2 folded into B)
          #pragma unroll
          for (int rg = 0; rg < 4; ++rg)
            dist[mt][pass * 4 + nt][rg] += __builtin_amdgcn_sqrtf(acc[rg]);
        }
      }
    }

    // late half of async-STAGE: convert + write next x tile into other buffer
    if (c + 1 < Cn) write_x(buf ^ 1);
    __syncthreads();  // one barrier per c-iter: publishes Xr writes + drains Bs DMA
  }

  // ---- min over windows, then global combine ----
  const int wql = w0 + wbase + quad * 4;
  #pragma unroll
  for (int nt2 = 0; nt2 < 8; ++nt2) {
    float v = 3.4e38f;
    #pragma unroll
    for (int mt = 0; mt < 2; ++mt)
      #pragma unroll
      for (int rg = 0; rg < 4; ++rg) {
        int wg = wql + mt * 16 + rg;
        float d = (wg < Wn) ? dist[mt][nt2][rg] : 3.4e38f;
        v = fminf(v, d);
      }
    v = fminf(v, __shfl_xor(v, 16, 64));
    v = fminf(v, __shfl_xor(v, 32, 64));
    if (lane < 16)
      atomicMin(&out[b * Kn + nt2 * 16 + n16], __float_as_uint(v));
  }
}

extern "C" void kernel_launch(void* const* d_in, const int* in_sizes, int n_in,
                              void* d_out, int out_size, void* d_ws, size_t ws_size,
                              hipStream_t stream) {
  const float* x  = (const float*)d_in[0];
  const float* sh = (const float*)d_in[1];
  unsigned int* out = (unsigned int*)d_out;
  unsigned short* hbf = (unsigned short*)d_ws;                      // 128 KB
  float* snorm = (float*)((char*)d_ws + (size_t)Cn * Kn * Sn * 2);  // +4 KB
  hipLaunchKernelGGL(prep_kernel, dim3(16), dim3(256), 0, stream, sh, out, hbf, snorm);
  hipLaunchKernelGGL(med_kernel, dim3(NWT, Bn), dim3(BDIM), 0, stream, x, hbf, snorm, out);
}